// Round 1
// 71.591 us; speedup vs baseline: 1.2097x; 1.2097x over previous
//
#include <hip/hip_runtime.h>

constexpr int B = 512;
// log2(e) / tau  with tau = 0.01
constexpr float INV_TAU_LOG2E = 144.26950408889634f;

// Only rows i with target[q,i]==1 contribute to ap[q]:
//   sim_pos_rk[q,i] = (sum_j sg*pos_mask + t_qi) * t_qi  -> zero when t_qi==0.
// Expected positives per row = B/N_CLASSES = 16, so compute only those rows.
__global__ __launch_bounds__(512) void smoothap_pos_rows(const float* __restrict__ scores,
                                                         const float* __restrict__ target,
                                                         float* __restrict__ ap_out) {
    const int q    = blockIdx.x;
    const int j    = threadIdx.x;
    const int lane = j & 63;
    const int wid  = j >> 6;

    __shared__ float s_sic[B];     // scores[q][j] * C
    __shared__ int   s_pos[B];     // compacted positive indices (worst-case B)
    __shared__ int   s_wcnt[8];    // per-wave positive counts
    __shared__ float s_pa[B * 8];  // per-positive per-wave partial sum_all
    __shared__ float s_pp[B * 8];  // per-positive per-wave partial sum_pos
    __shared__ float s_red[8];

    const float sic_j = scores[q * B + j] * INV_TAU_LOG2E;
    const float t_j   = target[q * B + j];
    const float w_j   = t_j - (j == q ? 1.0f : 0.0f);  // pos_mask[q,j]
    s_sic[j] = sic_j;

    // deterministic compaction of the positive set
    const bool is_pos = (t_j > 0.5f);
    const unsigned long long m = __ballot(is_pos);
    if (lane == 0) s_wcnt[wid] = __popcll(m);
    __syncthreads();

    int cnt = 0, base = 0;
#pragma unroll
    for (int w = 0; w < 8; ++w) {
        const int c = s_wcnt[w];
        if (w < wid) base += c;
        cnt += c;
    }
    if (is_pos) {
        const int r = __popcll(m & ((1ull << lane) - 1ull));
        s_pos[base + r] = j;
    }
    __syncthreads();

    // For each positive row i: all 512 threads evaluate their own j-term,
    // wave-reduce, stash per-wave partials. One barrier total.
    int p = 0;
    for (; p + 2 <= cnt; p += 2) {
        const float si0 = s_sic[s_pos[p]];
        const float si1 = s_sic[s_pos[p + 1]];
        // sg = sigmoid((s_j - s_i)/tau) = 1 / (1 + exp2((s_i - s_j)*C))
        const float e0 = __builtin_amdgcn_exp2f(si0 - sic_j);
        const float e1 = __builtin_amdgcn_exp2f(si1 - sic_j);
        const float g0 = __builtin_amdgcn_rcpf(1.0f + e0);
        const float g1 = __builtin_amdgcn_rcpf(1.0f + e1);
        float a0 = g0, b0 = g0 * w_j;
        float a1 = g1, b1 = g1 * w_j;
#pragma unroll
        for (int off = 32; off > 0; off >>= 1) {
            a0 += __shfl_down(a0, off, 64);
            b0 += __shfl_down(b0, off, 64);
            a1 += __shfl_down(a1, off, 64);
            b1 += __shfl_down(b1, off, 64);
        }
        if (lane == 0) {
            s_pa[p * 8 + wid]       = a0;  s_pp[p * 8 + wid]       = b0;
            s_pa[(p + 1) * 8 + wid] = a1;  s_pp[(p + 1) * 8 + wid] = b1;
        }
    }
    if (p < cnt) {
        const float si0 = s_sic[s_pos[p]];
        const float e0 = __builtin_amdgcn_exp2f(si0 - sic_j);
        const float g0 = __builtin_amdgcn_rcpf(1.0f + e0);
        float a0 = g0, b0 = g0 * w_j;
#pragma unroll
        for (int off = 32; off > 0; off >>= 1) {
            a0 += __shfl_down(a0, off, 64);
            b0 += __shfl_down(b0, off, 64);
        }
        if (lane == 0) { s_pa[p * 8 + wid] = a0; s_pp[p * 8 + wid] = b0; }
    }
    __syncthreads();

    // thread p (< cnt) finishes row s_pos[p]:
    //   sum_all includes j==i term (exactly 0.5), so sim_all_rk = a + 0.5
    //   sim_pos_rk = b + 1 (t_i == 1 on the positive set)
    float my_ap = 0.0f;
    if (j < cnt) {
        float a = 0.0f, bb = 0.0f;
#pragma unroll
        for (int w = 0; w < 8; ++w) { a += s_pa[j * 8 + w]; bb += s_pp[j * 8 + w]; }
        my_ap = (bb + 1.0f) / (a + 0.5f);
    }
#pragma unroll
    for (int off = 32; off > 0; off >>= 1) my_ap += __shfl_down(my_ap, off, 64);
    if (lane == 0) s_red[wid] = my_ap;
    __syncthreads();
    if (j == 0) {
        float r = 0.0f;
#pragma unroll
        for (int w = 0; w < 8; ++w) r += s_red[w];
        ap_out[q] = r / (float)cnt;   // / sum(target[q]) ; cnt >= 1 (diagonal)
    }
}

__global__ __launch_bounds__(512) void smoothap_final(const float* __restrict__ ap,
                                                      float* __restrict__ out) {
    float v = ap[threadIdx.x];
#pragma unroll
    for (int off = 32; off > 0; off >>= 1) v += __shfl_down(v, off, 64);
    __shared__ float red[8];
    const int lane = threadIdx.x & 63, wid = threadIdx.x >> 6;
    if (lane == 0) red[wid] = v;
    __syncthreads();
    if (threadIdx.x == 0) {
        float s = 0.0f;
#pragma unroll
        for (int w = 0; w < 8; ++w) s += red[w];
        out[0] = 1.0f - s / 512.0f;
    }
}

extern "C" void kernel_launch(void* const* d_in, const int* in_sizes, int n_in,
                              void* d_out, int out_size, void* d_ws, size_t ws_size,
                              hipStream_t stream) {
    const float* scores = (const float*)d_in[0];
    const float* target = (const float*)d_in[1];
    float* ap  = (float*)d_ws;   // 512 floats of scratch
    float* out = (float*)d_out;

    hipLaunchKernelGGL(smoothap_pos_rows, dim3(512), dim3(512), 0, stream, scores, target, ap);
    hipLaunchKernelGGL(smoothap_final, dim3(1), dim3(512), 0, stream, ap, out);
}

// Round 2
// 59.966 us; speedup vs baseline: 1.4442x; 1.1939x over previous
//
#include <hip/hip_runtime.h>

constexpr int B = 512;
// log2(e) / tau  with tau = 0.01
constexpr float INV_TAU_LOG2E = 144.26950408889634f;

// ap[q] = sum_{i in pos(q)} (sum_pos_i + 1) / (sum_all_i + 0.5) / |pos(q)|
// Only rows i with target[q,i]==1 contribute (the *target factor zeroes the rest).
// One wave owns (a pair of) positive rows end-to-end: register-resident row slice,
// one butterfly reduction per pair -> 8x fewer cross-lane ops than per-row block reduce.
__global__ __launch_bounds__(512) void smoothap_pos_rows(const float* __restrict__ scores,
                                                         const float* __restrict__ target,
                                                         float* __restrict__ ap_out) {
    const int q    = blockIdx.x;
    const int j    = threadIdx.x;
    const int lane = j & 63;
    const int wid  = j >> 6;

    __shared__ float2 s_sp[B];    // {scores[q][j]*C, pos_mask[q][j]}
    __shared__ int    s_pos[B];   // compacted positive indices
    __shared__ int    s_wcnt[8];  // per-wave positive counts
    __shared__ float  s_red[8];   // per-wave ap partials

    const float sic_j = scores[q * B + j] * INV_TAU_LOG2E;
    const float t_j   = target[q * B + j];
    const float w_j   = t_j - (j == q ? 1.0f : 0.0f);  // pos_mask[q,j]
    s_sp[j] = make_float2(sic_j, w_j);

    // deterministic compaction of the positive set
    const bool is_pos = (t_j > 0.5f);
    const unsigned long long m = __ballot(is_pos);
    if (lane == 0) s_wcnt[wid] = __popcll(m);
    __syncthreads();

    int cnt = 0, base = 0;
#pragma unroll
    for (int w = 0; w < 8; ++w) {
        const int c = s_wcnt[w];
        if (w < wid) base += c;
        cnt += c;
    }
    if (is_pos) {
        const int r = __popcll(m & ((1ull << lane) - 1ull));
        s_pos[base + r] = j;
    }
    __syncthreads();

    // preload this lane's column slice of the row into registers (reused for all rows)
    float sj[8], wj[8];
#pragma unroll
    for (int c = 0; c < 8; ++c) {
        const float2 v = s_sp[c * 64 + lane];
        sj[c] = v.x;
        wj[c] = v.y;
    }

    // wave wid handles positives {2*wid, 2*wid+1}, {2*wid+16, ...} (one pass when cnt<=16)
    float wap = 0.0f;
    for (int p = 2 * wid; p < cnt; p += 16) {
        const bool two = (p + 1 < cnt);
        const float si0 = s_sp[s_pos[p]].x;                    // wave-uniform broadcast
        const float si1 = two ? s_sp[s_pos[p + 1]].x : si0;
        float a0 = 0.0f, b0 = 0.0f, a1 = 0.0f, b1 = 0.0f;
#pragma unroll
        for (int c = 0; c < 8; ++c) {
            // sigmoid((s_j - s_i)/tau) = 1 / (1 + exp2((s_i - s_j)*C))
            const float e0 = __builtin_amdgcn_exp2f(si0 - sj[c]);
            const float e1 = __builtin_amdgcn_exp2f(si1 - sj[c]);
            const float g0 = __builtin_amdgcn_rcpf(1.0f + e0);
            const float g1 = __builtin_amdgcn_rcpf(1.0f + e1);
            a0 += g0;  b0 = fmaf(g0, wj[c], b0);
            a1 += g1;  b1 = fmaf(g1, wj[c], b1);
        }
#pragma unroll
        for (int off = 1; off < 64; off <<= 1) {
            a0 += __shfl_xor(a0, off, 64);
            b0 += __shfl_xor(b0, off, 64);
            a1 += __shfl_xor(a1, off, 64);
            b1 += __shfl_xor(b1, off, 64);
        }
        // j==i self-term contributes exactly 0.5 to a: sim_all_rk = a + 0.5
        // sim_pos_rk = b + 1 on the positive set
        wap += (b0 + 1.0f) / (a0 + 0.5f);
        if (two) wap += (b1 + 1.0f) / (a1 + 0.5f);
    }
    if (lane == 0) s_red[wid] = wap;
    __syncthreads();
    if (j == 0) {
        float r = 0.0f;
#pragma unroll
        for (int w = 0; w < 8; ++w) r += s_red[w];
        ap_out[q] = r / (float)cnt;   // / sum(target[q]); cnt >= 1 (diagonal)
    }
}

__global__ __launch_bounds__(64) void smoothap_final(const float* __restrict__ ap,
                                                     float* __restrict__ out) {
    const int l = threadIdx.x;
    float v = 0.0f;
#pragma unroll
    for (int c = 0; c < 8; ++c) v += ap[c * 64 + l];
#pragma unroll
    for (int off = 32; off > 0; off >>= 1) v += __shfl_down(v, off, 64);
    if (l == 0) out[0] = 1.0f - v * (1.0f / 512.0f);
}

extern "C" void kernel_launch(void* const* d_in, const int* in_sizes, int n_in,
                              void* d_out, int out_size, void* d_ws, size_t ws_size,
                              hipStream_t stream) {
    const float* scores = (const float*)d_in[0];
    const float* target = (const float*)d_in[1];
    float* ap  = (float*)d_ws;   // 512 floats of scratch
    float* out = (float*)d_out;

    hipLaunchKernelGGL(smoothap_pos_rows, dim3(512), dim3(512), 0, stream, scores, target, ap);
    hipLaunchKernelGGL(smoothap_final, dim3(1), dim3(64), 0, stream, ap, out);
}